// Round 1
// baseline (3263.573 us; speedup 1.0000x reference)
//
#include <hip/hip_runtime.h>

// GCN: N=100000 nodes, E=1600000 edges, F_IN=F_HID=64, F_OUT=16, fp32.
//
// Reformulation:
//   pairnorm(x) @ W = (x @ W) * rinv_row - (colmean(x) @ W)
//   graph_conv(h)   = scatter_dst(z[src]) + z + b,  where z = h @ W  (bias only on self term)
//
// Pipeline per layer (buffers A=z, B=agg, each N*64 floats in ws):
//   colsum -> cmW -> fused (rownorm + matvec + bias-init) -> atomic edge scatter
// Layer 3: no pairnorm, 64->16 matmul, scatter 16 floats/edge into d_out.

#define NFEAT 64

// ---------------- column sums (optional relu on load) ----------------
__global__ void colsum_kernel(const float* __restrict__ x, float* __restrict__ cs,
                              int n4, int relu) {
  // n4 = N*64/4 (float4 count). Column quad of float4 index i is (i & 15).
  __shared__ float lds[16][64];
  float s0 = 0.f, s1 = 0.f, s2 = 0.f, s3 = 0.f;
  const int t = threadIdx.x;
  const int stride = gridDim.x * blockDim.x;   // multiple of 16 -> column stays fixed
  for (int i = blockIdx.x * blockDim.x + t; i < n4; i += stride) {
    float4 v = ((const float4*)x)[i];
    if (relu) {
      v.x = fmaxf(v.x, 0.f); v.y = fmaxf(v.y, 0.f);
      v.z = fmaxf(v.z, 0.f); v.w = fmaxf(v.w, 0.f);
    }
    s0 += v.x; s1 += v.y; s2 += v.z; s3 += v.w;
  }
  const int r = t >> 4;          // 0..15
  const int cq = (t & 15) * 4;   // column base
  lds[r][cq + 0] = s0; lds[r][cq + 1] = s1; lds[r][cq + 2] = s2; lds[r][cq + 3] = s3;
  __syncthreads();
  if (t < 64) {
    float tot = 0.f;
    #pragma unroll
    for (int rr = 0; rr < 16; ++rr) tot += lds[rr][t];
    unsafeAtomicAdd(&cs[t], tot);
  }
}

// ---------------- cmW = (colsum/N) @ W  (64x64), one block of 64 ----------------
__global__ void cmw_kernel(const float* __restrict__ cs, const float* __restrict__ W,
                           float* __restrict__ cmW, int N) {
  const int lane = threadIdx.x;  // 0..63
  float acc = 0.f;
  #pragma unroll
  for (int k = 0; k < 64; ++k) acc = fmaf(cs[k], W[k * 64 + lane], acc);
  cmW[lane] = acc / (float)N;
}

// ------------- fused: z = (relu?(x) @ W) * rinv - cmW ; agg = z + b -------------
// Wave-per-row. Lane l holds x[row][l]; W column l staged in 64 VGPRs;
// inner product via v_readlane broadcast (VALU-only inner loop).
__global__ __launch_bounds__(256) void matnorm_kernel(
    const float* x, const float* __restrict__ W, const float* __restrict__ b,
    const float* __restrict__ cmW, float* __restrict__ z, float* agg,
    int N, int relu_in) {
  const int lane = threadIdx.x & 63;
  const int wid  = blockIdx.x * (blockDim.x >> 6) + (threadIdx.x >> 6);
  const int nw   = gridDim.x * (blockDim.x >> 6);

  float w[64];
  #pragma unroll
  for (int k = 0; k < 64; ++k) w[k] = W[k * 64 + lane];
  const float bl = b[lane];
  const float cm = cmW[lane];

  for (int row = wid; row < N; row += nw) {
    float xv = x[(size_t)row * 64 + lane];
    if (relu_in) xv = fmaxf(xv, 0.f);
    float ss = xv * xv;
    #pragma unroll
    for (int m = 1; m < 64; m <<= 1) ss += __shfl_xor(ss, m, 64);
    const float rinv = 1.0f / sqrtf(1e-6f + ss);
    float acc = 0.f;
    #pragma unroll
    for (int k = 0; k < 64; ++k) {
      const float xk = __builtin_bit_cast(
          float, __builtin_amdgcn_readlane(__builtin_bit_cast(int, xv), k));
      acc = fmaf(xk, w[k], acc);
    }
    const float zv = acc * rinv - cm;
    z[(size_t)row * 64 + lane]  = zv;
    agg[(size_t)row * 64 + lane] = zv + bl;   // self-loop + bias init
  }
}

// ------------- layer 3: z3 = relu(x) @ W3 (64->16); out = z3 + b3 -------------
__global__ __launch_bounds__(256) void mat16_kernel(
    const float* __restrict__ x, const float* __restrict__ W3,
    const float* __restrict__ b3, float* __restrict__ z3,
    float* __restrict__ out, int N) {
  const int lane = threadIdx.x & 63;
  const int j = lane & 15;
  const int wid = blockIdx.x * (blockDim.x >> 6) + (threadIdx.x >> 6);
  const int nw  = gridDim.x * (blockDim.x >> 6);

  float w[64];
  #pragma unroll
  for (int k = 0; k < 64; ++k) w[k] = W3[k * 16 + j];  // replicated 4x across lane quads
  const float bj = b3[j];

  for (int row = wid; row < N; row += nw) {
    const float xv = fmaxf(x[(size_t)row * 64 + lane], 0.f);
    float acc = 0.f;
    #pragma unroll
    for (int k = 0; k < 64; ++k) {
      const float xk = __builtin_bit_cast(
          float, __builtin_amdgcn_readlane(__builtin_bit_cast(int, xv), k));
      acc = fmaf(xk, w[k], acc);
    }
    if (lane < 16) {
      z3[(size_t)row * 16 + lane]  = acc;
      out[(size_t)row * 16 + lane] = acc + bj;
    }
  }
}

// ---------------- edge scatter: agg[dst] += z[src], 64 floats/edge ----------------
__global__ __launch_bounds__(256) void scatter64_kernel(
    const float* __restrict__ z, float* __restrict__ agg,
    const int* __restrict__ src, const int* __restrict__ dst, int E) {
  const int idx = blockIdx.x * blockDim.x + threadIdx.x;  // E*16 threads
  const int e = idx >> 4;
  const int fq = idx & 15;
  if (e >= E) return;
  const int s = src[e];
  const int d = dst[e];
  const float4 v = ((const float4*)z)[(size_t)s * 16 + fq];
  float* a = agg + (size_t)d * 64 + fq * 4;
  unsafeAtomicAdd(a + 0, v.x);
  unsafeAtomicAdd(a + 1, v.y);
  unsafeAtomicAdd(a + 2, v.z);
  unsafeAtomicAdd(a + 3, v.w);
}

// ---------------- edge scatter, 16 floats/edge (layer 3) ----------------
__global__ __launch_bounds__(256) void scatter16_kernel(
    const float* __restrict__ z, float* __restrict__ out,
    const int* __restrict__ src, const int* __restrict__ dst, int E) {
  const int idx = blockIdx.x * blockDim.x + threadIdx.x;  // E*4 threads
  const int e = idx >> 2;
  const int fq = idx & 3;
  if (e >= E) return;
  const int s = src[e];
  const int d = dst[e];
  const float4 v = ((const float4*)z)[(size_t)s * 4 + fq];
  float* a = out + (size_t)d * 16 + fq * 4;
  unsafeAtomicAdd(a + 0, v.x);
  unsafeAtomicAdd(a + 1, v.y);
  unsafeAtomicAdd(a + 2, v.z);
  unsafeAtomicAdd(a + 3, v.w);
}

extern "C" void kernel_launch(void* const* d_in, const int* in_sizes, int n_in,
                              void* d_out, int out_size, void* d_ws, size_t ws_size,
                              hipStream_t stream) {
  const float* feat = (const float*)d_in[0];
  const float* W1 = (const float*)d_in[1];
  const float* b1 = (const float*)d_in[2];
  const float* W2 = (const float*)d_in[3];
  const float* b2 = (const float*)d_in[4];
  const float* W3 = (const float*)d_in[5];
  const float* b3 = (const float*)d_in[6];
  const int* src = (const int*)d_in[7];
  const int* dst = (const int*)d_in[8];
  const int N = in_sizes[0] / 64;
  const int E = in_sizes[7];
  float* out = (float*)d_out;

  float* A   = (float*)d_ws;            // z buffer, N*64
  float* B   = A + (size_t)N * 64;      // agg buffer, N*64
  float* cs  = B + (size_t)N * 64;      // 64 column sums
  float* cmW = cs + 64;                 // 64

  const int sc64_blocks = (E * 16 + 255) / 256;
  const int sc16_blocks = (E * 4 + 255) / 256;

  // ---- layer 1 ----
  hipMemsetAsync(cs, 0, 64 * sizeof(float), stream);
  colsum_kernel<<<512, 256, 0, stream>>>(feat, cs, N * 16, 0);
  cmw_kernel<<<1, 64, 0, stream>>>(cs, W1, cmW, N);
  matnorm_kernel<<<1024, 256, 0, stream>>>(feat, W1, b1, cmW, A, B, N, 0);
  scatter64_kernel<<<sc64_blocks, 256, 0, stream>>>(A, B, src, dst, E);

  // ---- layer 2 (relu applied on read of B = agg1; agg2 overwrites B in place,
  // safe: each row is read then written by exactly one wave) ----
  hipMemsetAsync(cs, 0, 64 * sizeof(float), stream);
  colsum_kernel<<<512, 256, 0, stream>>>(B, cs, N * 16, 1);
  cmw_kernel<<<1, 64, 0, stream>>>(cs, W2, cmW, N);
  matnorm_kernel<<<1024, 256, 0, stream>>>(B, W2, b2, cmW, A, B, N, 1);
  scatter64_kernel<<<sc64_blocks, 256, 0, stream>>>(A, B, src, dst, E);

  // ---- layer 3: out = scatter(z3[src]) + z3 + b3, z3 = relu(agg2) @ W3 ----
  mat16_kernel<<<1024, 256, 0, stream>>>(B, W3, b3, A, out, N);
  scatter16_kernel<<<sc16_blocks, 256, 0, stream>>>(A, out, src, dst, E);
}

// Round 2
// 605.578 us; speedup vs baseline: 5.3892x; 5.3892x over previous
//
#include <hip/hip_runtime.h>

// GCN: N=100000 nodes, E=1600000 edges, F_IN=F_HID=64, F_OUT=16, fp32.
//
// Reformulation:
//   pairnorm(x) @ W = (x @ W) * rinv_row - (colmean(x) @ W)
//   graph_conv(h)   = gather_dst(z[src]) + z + b,  where z = h @ W
//
// R1 -> R2: scatter64 (102M fp atomics, 1.6 GB writeback from XCD L2
// ping-pong, 1355 us each) replaced by CSR-by-dst build (int atomics only)
// + non-atomic per-node gather. Gather also applies self-loop + bias, so
// matnorm only writes z.

// ---------------- column sums (optional relu on load) ----------------
__global__ void colsum_kernel(const float* __restrict__ x, float* __restrict__ cs,
                              int n4, int relu) {
  __shared__ float lds[16][64];
  float s0 = 0.f, s1 = 0.f, s2 = 0.f, s3 = 0.f;
  const int t = threadIdx.x;
  const int stride = gridDim.x * blockDim.x;   // multiple of 16 -> column fixed
  for (int i = blockIdx.x * blockDim.x + t; i < n4; i += stride) {
    float4 v = ((const float4*)x)[i];
    if (relu) {
      v.x = fmaxf(v.x, 0.f); v.y = fmaxf(v.y, 0.f);
      v.z = fmaxf(v.z, 0.f); v.w = fmaxf(v.w, 0.f);
    }
    s0 += v.x; s1 += v.y; s2 += v.z; s3 += v.w;
  }
  const int r = t >> 4;
  const int cq = (t & 15) * 4;
  lds[r][cq + 0] = s0; lds[r][cq + 1] = s1; lds[r][cq + 2] = s2; lds[r][cq + 3] = s3;
  __syncthreads();
  if (t < 64) {
    float tot = 0.f;
    #pragma unroll
    for (int rr = 0; rr < 16; ++rr) tot += lds[rr][t];
    unsafeAtomicAdd(&cs[t], tot);
  }
}

// ---------------- cmW = (colsum/N) @ W (64x64) ----------------
__global__ void cmw_kernel(const float* __restrict__ cs, const float* __restrict__ W,
                           float* __restrict__ cmW, int N) {
  const int lane = threadIdx.x;
  float acc = 0.f;
  #pragma unroll
  for (int k = 0; k < 64; ++k) acc = fmaf(cs[k], W[k * 64 + lane], acc);
  cmW[lane] = acc / (float)N;
}

// ------------- fused: z = (relu?(x) @ W) * rinv - cmW -------------
__global__ __launch_bounds__(256) void matnorm_kernel(
    const float* x, const float* __restrict__ W,
    const float* __restrict__ cmW, float* __restrict__ z,
    int N, int relu_in) {
  const int lane = threadIdx.x & 63;
  const int wid  = blockIdx.x * (blockDim.x >> 6) + (threadIdx.x >> 6);
  const int nw   = gridDim.x * (blockDim.x >> 6);

  float w[64];
  #pragma unroll
  for (int k = 0; k < 64; ++k) w[k] = W[k * 64 + lane];
  const float cm = cmW[lane];

  for (int row = wid; row < N; row += nw) {
    float xv = x[(size_t)row * 64 + lane];
    if (relu_in) xv = fmaxf(xv, 0.f);
    float ss = xv * xv;
    #pragma unroll
    for (int m = 1; m < 64; m <<= 1) ss += __shfl_xor(ss, m, 64);
    const float rinv = 1.0f / sqrtf(1e-6f + ss);
    float acc = 0.f;
    #pragma unroll
    for (int k = 0; k < 64; ++k) {
      const float xk = __builtin_bit_cast(
          float, __builtin_amdgcn_readlane(__builtin_bit_cast(int, xv), k));
      acc = fmaf(xk, w[k], acc);
    }
    z[(size_t)row * 64 + lane] = acc * rinv - cm;
  }
}

// ------------- layer 3 matmul only: z3 = relu(x) @ W3 (64->16) -------------
__global__ __launch_bounds__(256) void mat16_kernel(
    const float* __restrict__ x, const float* __restrict__ W3,
    float* __restrict__ z3, int N) {
  const int lane = threadIdx.x & 63;
  const int j = lane & 15;
  const int wid = blockIdx.x * (blockDim.x >> 6) + (threadIdx.x >> 6);
  const int nw  = gridDim.x * (blockDim.x >> 6);

  float w[64];
  #pragma unroll
  for (int k = 0; k < 64; ++k) w[k] = W3[k * 16 + j];
  for (int row = wid; row < N; row += nw) {
    const float xv = fmaxf(x[(size_t)row * 64 + lane], 0.f);
    float acc = 0.f;
    #pragma unroll
    for (int k = 0; k < 64; ++k) {
      const float xk = __builtin_bit_cast(
          float, __builtin_amdgcn_readlane(__builtin_bit_cast(int, xv), k));
      acc = fmaf(xk, w[k], acc);
    }
    if (lane < 16) z3[(size_t)row * 16 + lane] = acc;
  }
}

// ---------------- CSR build ----------------
__global__ void hist_kernel(const int* __restrict__ dst, int* __restrict__ deg, int E) {
  const int stride = gridDim.x * blockDim.x;
  for (int e = blockIdx.x * blockDim.x + threadIdx.x; e < E; e += stride)
    atomicAdd(&deg[dst[e]], 1);
}

__global__ void blocksum_kernel(const int* __restrict__ deg, int* __restrict__ bsum, int N) {
  __shared__ int lds[256];
  const int idx = blockIdx.x * 256 + threadIdx.x;
  lds[threadIdx.x] = (idx < N) ? deg[idx] : 0;
  __syncthreads();
  for (int off = 128; off > 0; off >>= 1) {
    if (threadIdx.x < off) lds[threadIdx.x] += lds[threadIdx.x + off];
    __syncthreads();
  }
  if (threadIdx.x == 0) bsum[blockIdx.x] = lds[0];
}

// exclusive scan of bsum[NB] in one block of 512 (NB <= 512)
__global__ void scanbsum_kernel(int* __restrict__ bsum, int NB) {
  __shared__ int s[512];
  const int t = threadIdx.x;
  s[t] = (t < NB) ? bsum[t] : 0;
  __syncthreads();
  for (int off = 1; off < 512; off <<= 1) {
    int v = (t >= off) ? s[t - off] : 0;
    __syncthreads();
    s[t] += v;
    __syncthreads();
  }
  if (t < NB) bsum[t] = (t == 0) ? 0 : s[t - 1];  // exclusive
}

__global__ void rowstart_kernel(const int* __restrict__ deg, const int* __restrict__ bsum,
                                int* __restrict__ rowstart, int* __restrict__ cursor,
                                int N, int E) {
  __shared__ int s[256];
  const int t = threadIdx.x;
  const int idx = blockIdx.x * 256 + t;
  const int d = (idx < N) ? deg[idx] : 0;
  s[t] = d;
  __syncthreads();
  for (int off = 1; off < 256; off <<= 1) {
    int v = (t >= off) ? s[t - off] : 0;
    __syncthreads();
    s[t] += v;
    __syncthreads();
  }
  if (idx < N) {
    const int rs = bsum[blockIdx.x] + s[t] - d;  // exclusive
    rowstart[idx] = rs;
    cursor[idx] = rs;
    if (idx == N - 1) rowstart[N] = E;
  }
}

__global__ void fill_kernel(const int* __restrict__ src, const int* __restrict__ dst,
                            int* __restrict__ cursor, int* __restrict__ csr, int E) {
  const int stride = gridDim.x * blockDim.x;
  for (int e = blockIdx.x * blockDim.x + threadIdx.x; e < E; e += stride) {
    const int pos = atomicAdd(&cursor[dst[e]], 1);
    csr[pos] = src[e];
  }
}

// ------- gather64: agg[d] = z[d] + b + sum_{e in CSR[d]} z[src_e], wave/node -------
__global__ __launch_bounds__(256) void gather64_kernel(
    const float* __restrict__ z, const float* __restrict__ b,
    const int* __restrict__ rowstart, const int* __restrict__ csr,
    float* __restrict__ agg, int N) {
  const int lane = threadIdx.x & 63;
  int node = blockIdx.x * (blockDim.x >> 6) + (threadIdx.x >> 6);
  if (node >= N) return;
  node = __builtin_amdgcn_readfirstlane(node);  // wave-uniform -> scalar loads
  const int start = rowstart[node];
  const int end   = rowstart[node + 1];
  float a0 = 0.f, a1 = 0.f, a2 = 0.f, a3 = 0.f;
  int e = start;
  for (; e + 4 <= end; e += 4) {
    const int s0 = csr[e + 0], s1 = csr[e + 1], s2 = csr[e + 2], s3 = csr[e + 3];
    a0 += z[(size_t)s0 * 64 + lane];
    a1 += z[(size_t)s1 * 64 + lane];
    a2 += z[(size_t)s2 * 64 + lane];
    a3 += z[(size_t)s3 * 64 + lane];
  }
  for (; e < end; ++e) a0 += z[(size_t)csr[e] * 64 + lane];
  const float sum = (a0 + a1) + (a2 + a3);
  agg[(size_t)node * 64 + lane] = z[(size_t)node * 64 + lane] + b[lane] + sum;
}

// ------- gather16: out[d] = z3[d] + b3 + sum z3[src]; 16 feat x 4 edge-groups -------
__global__ __launch_bounds__(256) void gather16_kernel(
    const float* __restrict__ z3, const float* __restrict__ b3,
    const int* __restrict__ rowstart, const int* __restrict__ csr,
    float* __restrict__ out, int N) {
  const int lane = threadIdx.x & 63;
  const int f = lane & 15;
  const int g = lane >> 4;
  int node = blockIdx.x * (blockDim.x >> 6) + (threadIdx.x >> 6);
  if (node >= N) return;
  node = __builtin_amdgcn_readfirstlane(node);
  const int start = rowstart[node];
  const int end   = rowstart[node + 1];
  float acc = 0.f;
  for (int e = start + g; e < end; e += 4)
    acc += z3[(size_t)csr[e] * 16 + f];
  acc += __shfl_xor(acc, 16, 64);
  acc += __shfl_xor(acc, 32, 64);
  if (lane < 16)
    out[(size_t)node * 16 + f] = z3[(size_t)node * 16 + f] + b3[f] + acc;
}

extern "C" void kernel_launch(void* const* d_in, const int* in_sizes, int n_in,
                              void* d_out, int out_size, void* d_ws, size_t ws_size,
                              hipStream_t stream) {
  const float* feat = (const float*)d_in[0];
  const float* W1 = (const float*)d_in[1];
  const float* b1 = (const float*)d_in[2];
  const float* W2 = (const float*)d_in[3];
  const float* b2 = (const float*)d_in[4];
  const float* W3 = (const float*)d_in[5];
  const float* b3 = (const float*)d_in[6];
  const int* src = (const int*)d_in[7];
  const int* dst = (const int*)d_in[8];
  const int N = in_sizes[0] / 64;
  const int E = in_sizes[7];
  float* out = (float*)d_out;

  // workspace layout
  float* A   = (float*)d_ws;            // z buffer, N*64
  float* B   = A + (size_t)N * 64;      // agg buffer, N*64
  float* cs  = B + (size_t)N * 64;      // 64
  float* cmW = cs + 64;                 // 64
  int* deg      = (int*)(cmW + 64);     // N
  int* rowstart = deg + N;              // N+1
  int* cursor   = rowstart + N + 1;     // N
  int* bsum     = cursor + N;           // <=512
  int* csr      = bsum + 512;           // E

  const int NB = (N + 255) / 256;       // 391 <= 512
  const int node_blocks = (N + 3) / 4;  // 4 waves of 64 per block

  // ---- CSR build (once per call; ws re-poisoned each call) ----
  hipMemsetAsync(deg, 0, (size_t)N * sizeof(int), stream);
  hist_kernel<<<1024, 256, 0, stream>>>(dst, deg, E);
  blocksum_kernel<<<NB, 256, 0, stream>>>(deg, bsum, N);
  scanbsum_kernel<<<1, 512, 0, stream>>>(bsum, NB);
  rowstart_kernel<<<NB, 256, 0, stream>>>(deg, bsum, rowstart, cursor, N, E);
  fill_kernel<<<1024, 256, 0, stream>>>(src, dst, cursor, csr, E);

  // ---- layer 1 ----
  hipMemsetAsync(cs, 0, 64 * sizeof(float), stream);
  colsum_kernel<<<512, 256, 0, stream>>>(feat, cs, N * 16, 0);
  cmw_kernel<<<1, 64, 0, stream>>>(cs, W1, cmW, N);
  matnorm_kernel<<<1024, 256, 0, stream>>>(feat, W1, cmW, A, N, 0);
  gather64_kernel<<<node_blocks, 256, 0, stream>>>(A, b1, rowstart, csr, B, N);

  // ---- layer 2 (relu on read of B; z2 -> A; agg2 -> B in place) ----
  hipMemsetAsync(cs, 0, 64 * sizeof(float), stream);
  colsum_kernel<<<512, 256, 0, stream>>>(B, cs, N * 16, 1);
  cmw_kernel<<<1, 64, 0, stream>>>(cs, W2, cmW, N);
  matnorm_kernel<<<1024, 256, 0, stream>>>(B, W2, cmW, A, N, 1);
  gather64_kernel<<<node_blocks, 256, 0, stream>>>(A, b2, rowstart, csr, B, N);

  // ---- layer 3 ----
  mat16_kernel<<<1024, 256, 0, stream>>>(B, W3, A, N);
  gather16_kernel<<<node_blocks, 256, 0, stream>>>(A, b3, rowstart, csr, out, N);
}

// Round 3
// 550.263 us; speedup vs baseline: 5.9309x; 1.1005x over previous
//
#include <hip/hip_runtime.h>

// GCN: N=100000 nodes, E=1600000 edges, F_IN=F_HID=64, F_OUT=16, fp32.
//
// Reformulation:
//   pairnorm(x) @ W = (x @ W) * rinv_row - (colmean(x) @ W)
//   graph_conv(h)   = gather_dst(z[src]) + z + b,  where z = h @ W
//
// R2 -> R3: hist/fill had 15x write amplification (WRITE_SIZE 106 MB vs
// 6.8 MB logical) from cross-XCD line ping-pong on scattered atomic writes.
// Fix: dst-range partitioning with part = blockIdx%8 (round-robin XCD
// heuristic) so each csr/deg/cursor region is touched by one XCD only.
// Edges are re-read 8x (L2/L3-served) in exchange for XCD-local writes.

// ---------------- column sums (optional relu on load) ----------------
__global__ void colsum_kernel(const float* __restrict__ x, float* __restrict__ cs,
                              int n4, int relu) {
  __shared__ float lds[16][64];
  float s0 = 0.f, s1 = 0.f, s2 = 0.f, s3 = 0.f;
  const int t = threadIdx.x;
  const int stride = gridDim.x * blockDim.x;   // multiple of 16 -> column fixed
  for (int i = blockIdx.x * blockDim.x + t; i < n4; i += stride) {
    float4 v = ((const float4*)x)[i];
    if (relu) {
      v.x = fmaxf(v.x, 0.f); v.y = fmaxf(v.y, 0.f);
      v.z = fmaxf(v.z, 0.f); v.w = fmaxf(v.w, 0.f);
    }
    s0 += v.x; s1 += v.y; s2 += v.z; s3 += v.w;
  }
  const int r = t >> 4;
  const int cq = (t & 15) * 4;
  lds[r][cq + 0] = s0; lds[r][cq + 1] = s1; lds[r][cq + 2] = s2; lds[r][cq + 3] = s3;
  __syncthreads();
  if (t < 64) {
    float tot = 0.f;
    #pragma unroll
    for (int rr = 0; rr < 16; ++rr) tot += lds[rr][t];
    unsafeAtomicAdd(&cs[t], tot);
  }
}

// ---------------- cmW = (colsum/N) @ W (64x64) ----------------
__global__ void cmw_kernel(const float* __restrict__ cs, const float* __restrict__ W,
                           float* __restrict__ cmW, int N) {
  const int lane = threadIdx.x;
  float acc = 0.f;
  #pragma unroll
  for (int k = 0; k < 64; ++k) acc = fmaf(cs[k], W[k * 64 + lane], acc);
  cmW[lane] = acc / (float)N;
}

// ------------- fused: z = (relu?(x) @ W) * rinv - cmW -------------
__global__ __launch_bounds__(256) void matnorm_kernel(
    const float* x, const float* __restrict__ W,
    const float* __restrict__ cmW, float* __restrict__ z,
    int N, int relu_in) {
  const int lane = threadIdx.x & 63;
  const int wid  = blockIdx.x * (blockDim.x >> 6) + (threadIdx.x >> 6);
  const int nw   = gridDim.x * (blockDim.x >> 6);

  float w[64];
  #pragma unroll
  for (int k = 0; k < 64; ++k) w[k] = W[k * 64 + lane];
  const float cm = cmW[lane];

  for (int row = wid; row < N; row += nw) {
    float xv = x[(size_t)row * 64 + lane];
    if (relu_in) xv = fmaxf(xv, 0.f);
    float ss = xv * xv;
    #pragma unroll
    for (int m = 1; m < 64; m <<= 1) ss += __shfl_xor(ss, m, 64);
    const float rinv = 1.0f / sqrtf(1e-6f + ss);
    float acc = 0.f;
    #pragma unroll
    for (int k = 0; k < 64; ++k) {
      const float xk = __builtin_bit_cast(
          float, __builtin_amdgcn_readlane(__builtin_bit_cast(int, xv), k));
      acc = fmaf(xk, w[k], acc);
    }
    z[(size_t)row * 64 + lane] = acc * rinv - cm;
  }
}

// ------------- layer 3 matmul only: z3 = relu(x) @ W3 (64->16) -------------
__global__ __launch_bounds__(256) void mat16_kernel(
    const float* __restrict__ x, const float* __restrict__ W3,
    float* __restrict__ z3, int N) {
  const int lane = threadIdx.x & 63;
  const int j = lane & 15;
  const int wid = blockIdx.x * (blockDim.x >> 6) + (threadIdx.x >> 6);
  const int nw  = gridDim.x * (blockDim.x >> 6);

  float w[64];
  #pragma unroll
  for (int k = 0; k < 64; ++k) w[k] = W3[k * 16 + j];
  for (int row = wid; row < N; row += nw) {
    const float xv = fmaxf(x[(size_t)row * 64 + lane], 0.f);
    float acc = 0.f;
    #pragma unroll
    for (int k = 0; k < 64; ++k) {
      const float xk = __builtin_bit_cast(
          float, __builtin_amdgcn_readlane(__builtin_bit_cast(int, xv), k));
      acc = fmaf(xk, w[k], acc);
    }
    if (lane < 16) z3[(size_t)row * 16 + lane] = acc;
  }
}

// ---------------- CSR build, XCD-partitioned ----------------
// part = blockIdx%8 -> (heuristically) one XCD per dst-slice; all atomics and
// scattered writes for a slice stay in that XCD's L2.
__global__ __launch_bounds__(256) void hist_part_kernel(
    const int* __restrict__ dst, int* __restrict__ deg, int E, int N) {
  const int part  = blockIdx.x & 7;
  const int lo    = (int)(((long long)N * part) >> 3);
  const int hi    = (int)(((long long)N * (part + 1)) >> 3);
  const int slice = blockIdx.x >> 3;
  const int stride = (gridDim.x >> 3) * blockDim.x;
  for (int e = slice * blockDim.x + threadIdx.x; e < E; e += stride) {
    const int d = dst[e];
    if (d >= lo && d < hi) atomicAdd(&deg[d], 1);
  }
}

__global__ void blocksum_kernel(const int* __restrict__ deg, int* __restrict__ bsum, int N) {
  __shared__ int lds[256];
  const int idx = blockIdx.x * 256 + threadIdx.x;
  lds[threadIdx.x] = (idx < N) ? deg[idx] : 0;
  __syncthreads();
  for (int off = 128; off > 0; off >>= 1) {
    if (threadIdx.x < off) lds[threadIdx.x] += lds[threadIdx.x + off];
    __syncthreads();
  }
  if (threadIdx.x == 0) bsum[blockIdx.x] = lds[0];
}

// exclusive scan of bsum[NB] in one block of 512 (NB <= 512)
__global__ void scanbsum_kernel(int* __restrict__ bsum, int NB) {
  __shared__ int s[512];
  const int t = threadIdx.x;
  s[t] = (t < NB) ? bsum[t] : 0;
  __syncthreads();
  for (int off = 1; off < 512; off <<= 1) {
    int v = (t >= off) ? s[t - off] : 0;
    __syncthreads();
    s[t] += v;
    __syncthreads();
  }
  if (t < NB) bsum[t] = (t == 0) ? 0 : s[t - 1];  // exclusive
}

__global__ void rowstart_kernel(const int* __restrict__ deg, const int* __restrict__ bsum,
                                int* __restrict__ rowstart, int* __restrict__ cursor,
                                int N, int E) {
  __shared__ int s[256];
  const int t = threadIdx.x;
  const int idx = blockIdx.x * 256 + t;
  const int d = (idx < N) ? deg[idx] : 0;
  s[t] = d;
  __syncthreads();
  for (int off = 1; off < 256; off <<= 1) {
    int v = (t >= off) ? s[t - off] : 0;
    __syncthreads();
    s[t] += v;
    __syncthreads();
  }
  if (idx < N) {
    const int rs = bsum[blockIdx.x] + s[t] - d;  // exclusive
    rowstart[idx] = rs;
    cursor[idx] = rs;
    if (idx == N - 1) rowstart[N] = E;
  }
}

__global__ __launch_bounds__(256) void fill_part_kernel(
    const int* __restrict__ src, const int* __restrict__ dst,
    int* __restrict__ cursor, int* __restrict__ csr, int E, int N) {
  const int part  = blockIdx.x & 7;
  const int lo    = (int)(((long long)N * part) >> 3);
  const int hi    = (int)(((long long)N * (part + 1)) >> 3);
  const int slice = blockIdx.x >> 3;
  const int stride = (gridDim.x >> 3) * blockDim.x;
  for (int e = slice * blockDim.x + threadIdx.x; e < E; e += stride) {
    const int d = dst[e];
    if (d >= lo && d < hi) {
      const int pos = atomicAdd(&cursor[d], 1);
      csr[pos] = src[e];
    }
  }
}

// ------- gather64: agg[d] = z[d] + b + sum_{e in CSR[d]} z[src_e], wave/node -------
__global__ __launch_bounds__(256) void gather64_kernel(
    const float* __restrict__ z, const float* __restrict__ b,
    const int* __restrict__ rowstart, const int* __restrict__ csr,
    float* __restrict__ agg, int N) {
  const int lane = threadIdx.x & 63;
  int node = blockIdx.x * (blockDim.x >> 6) + (threadIdx.x >> 6);
  if (node >= N) return;
  node = __builtin_amdgcn_readfirstlane(node);  // wave-uniform -> scalar loads
  const int start = rowstart[node];
  const int end   = rowstart[node + 1];
  float a0 = 0.f, a1 = 0.f, a2 = 0.f, a3 = 0.f;
  int e = start;
  for (; e + 4 <= end; e += 4) {
    const int s0 = csr[e + 0], s1 = csr[e + 1], s2 = csr[e + 2], s3 = csr[e + 3];
    a0 += z[(size_t)s0 * 64 + lane];
    a1 += z[(size_t)s1 * 64 + lane];
    a2 += z[(size_t)s2 * 64 + lane];
    a3 += z[(size_t)s3 * 64 + lane];
  }
  for (; e < end; ++e) a0 += z[(size_t)csr[e] * 64 + lane];
  const float sum = (a0 + a1) + (a2 + a3);
  agg[(size_t)node * 64 + lane] = z[(size_t)node * 64 + lane] + b[lane] + sum;
}

// ------- gather16: out[d] = z3[d] + b3 + sum z3[src]; 16 feat x 4 edge-groups -------
__global__ __launch_bounds__(256) void gather16_kernel(
    const float* __restrict__ z3, const float* __restrict__ b3,
    const int* __restrict__ rowstart, const int* __restrict__ csr,
    float* __restrict__ out, int N) {
  const int lane = threadIdx.x & 63;
  const int f = lane & 15;
  const int g = lane >> 4;
  int node = blockIdx.x * (blockDim.x >> 6) + (threadIdx.x >> 6);
  if (node >= N) return;
  node = __builtin_amdgcn_readfirstlane(node);
  const int start = rowstart[node];
  const int end   = rowstart[node + 1];
  float acc = 0.f;
  for (int e = start + g; e < end; e += 4)
    acc += z3[(size_t)csr[e] * 16 + f];
  acc += __shfl_xor(acc, 16, 64);
  acc += __shfl_xor(acc, 32, 64);
  if (lane < 16)
    out[(size_t)node * 16 + f] = z3[(size_t)node * 16 + f] + b3[f] + acc;
}

extern "C" void kernel_launch(void* const* d_in, const int* in_sizes, int n_in,
                              void* d_out, int out_size, void* d_ws, size_t ws_size,
                              hipStream_t stream) {
  const float* feat = (const float*)d_in[0];
  const float* W1 = (const float*)d_in[1];
  const float* b1 = (const float*)d_in[2];
  const float* W2 = (const float*)d_in[3];
  const float* b2 = (const float*)d_in[4];
  const float* W3 = (const float*)d_in[5];
  const float* b3 = (const float*)d_in[6];
  const int* src = (const int*)d_in[7];
  const int* dst = (const int*)d_in[8];
  const int N = in_sizes[0] / 64;
  const int E = in_sizes[7];
  float* out = (float*)d_out;

  // workspace layout
  float* A   = (float*)d_ws;            // z buffer, N*64
  float* B   = A + (size_t)N * 64;      // agg buffer, N*64
  float* cs  = B + (size_t)N * 64;      // 64
  float* cmW = cs + 64;                 // 64
  int* deg      = (int*)(cmW + 64);     // N
  int* rowstart = deg + N;              // N+1
  int* cursor   = rowstart + N + 1;     // N
  int* bsum     = cursor + N;           // <=512
  int* csr      = bsum + 512;           // E

  const int NB = (N + 255) / 256;       // 391 <= 512
  const int node_blocks = (N + 3) / 4;  // 4 waves of 64 per block

  // ---- CSR build (once per call; ws re-poisoned each call) ----
  hipMemsetAsync(deg, 0, (size_t)N * sizeof(int), stream);
  hist_part_kernel<<<2048, 256, 0, stream>>>(dst, deg, E, N);
  blocksum_kernel<<<NB, 256, 0, stream>>>(deg, bsum, N);
  scanbsum_kernel<<<1, 512, 0, stream>>>(bsum, NB);
  rowstart_kernel<<<NB, 256, 0, stream>>>(deg, bsum, rowstart, cursor, N, E);
  fill_part_kernel<<<2048, 256, 0, stream>>>(src, dst, cursor, csr, E, N);

  // ---- layer 1 ----
  hipMemsetAsync(cs, 0, 64 * sizeof(float), stream);
  colsum_kernel<<<512, 256, 0, stream>>>(feat, cs, N * 16, 0);
  cmw_kernel<<<1, 64, 0, stream>>>(cs, W1, cmW, N);
  matnorm_kernel<<<1024, 256, 0, stream>>>(feat, W1, cmW, A, N, 0);
  gather64_kernel<<<node_blocks, 256, 0, stream>>>(A, b1, rowstart, csr, B, N);

  // ---- layer 2 (relu on read of B; z2 -> A; agg2 -> B in place) ----
  hipMemsetAsync(cs, 0, 64 * sizeof(float), stream);
  colsum_kernel<<<512, 256, 0, stream>>>(B, cs, N * 16, 1);
  cmw_kernel<<<1, 64, 0, stream>>>(cs, W2, cmW, N);
  matnorm_kernel<<<1024, 256, 0, stream>>>(B, W2, cmW, A, N, 1);
  gather64_kernel<<<node_blocks, 256, 0, stream>>>(A, b2, rowstart, csr, B, N);

  // ---- layer 3 ----
  mat16_kernel<<<1024, 256, 0, stream>>>(B, W3, A, N);
  gather16_kernel<<<node_blocks, 256, 0, stream>>>(A, b3, rowstart, csr, out, N);
}